// Round 6
// baseline (3520.375 us; speedup 1.0000x reference)
//
#include <hip/hip_runtime.h>

// ===========================================================================
// Compile-time construction of the e3nn real Wigner-3j path tensor.
// (numerically validated rounds 3-5: absmax 0.031 vs threshold 0.259)
// ===========================================================================
namespace cg {

constexpr double csqrt(double x) {
    double g = x < 1.0 ? 1.0 : x;
    for (int i = 0; i < 64; ++i) g = 0.5 * (g + x / g);
    return g;
}
constexpr double fact(int n) { double r = 1.0; for (int i = 2; i <= n; ++i) r *= (double)i; return r; }

constexpr double su2cg(int j1, int j2, int j3, int m1, int m2, int m3) {
    if (m1 + m2 != m3) return 0.0;
    double pre = csqrt((2.0*j3+1.0)*fact(j3+j1-j2)*fact(j3-j1+j2)*fact(j1+j2-j3)
                       *fact(j3+m3)*fact(j3-m3)
                       /(fact(j1+j2+j3+1)*fact(j1-m1)*fact(j1+m1)*fact(j2-m2)*fact(j2+m2)));
    double S = 0.0;
    for (int v = 0; v <= j1 + j2 + j3; ++v) {
        int b1 = j3-j1+j2-v, b2 = j3+m3-v, b3 = v+j1-j2-m3, b4 = j2+j3+m1-v, b5 = j1-m1+v;
        if (b1 < 0 || b2 < 0 || b3 < 0 || b4 < 0 || b5 < 0) continue;
        double term = fact(b4)*fact(b5)/(fact(v)*fact(b1)*fact(b2)*fact(b3));
        S += ((v + j2 + m2) & 1) ? -term : term;
    }
    return pre * S;
}

struct CD { double re, im; };
constexpr CD cmul(CD a, CD b) { return { a.re*b.re - a.im*b.im, a.re*b.im + a.im*b.re }; }

constexpr CD qent(int l, int r, int c) {
    const double s = 0.70710678118654752440;
    CD v{0.0, 0.0};
    int m = r - l;
    if (m < 0)       { if (c == l - m) v = { s, 0.0 }; else if (c == l + m) v = { 0.0, -s }; }
    else if (m == 0) { if (c == l)     v = { 1.0, 0.0 }; }
    else             { double sg = (m & 1) ? -1.0 : 1.0;
                       if (c == l + m) v = { sg*s, 0.0 }; else if (c == l - m) v = { 0.0, sg*s }; }
    if      (l == 1) v = { v.im, -v.re };
    else if (l == 2) v = { -v.re, -v.im };
    return v;
}

constexpr int PA_[11] = {0,0,0,1,1,1,1,2,2,2,2};
constexpr int PB_[11] = {0,1,2,0,1,1,2,0,1,2,2};
constexpr int PC_[11] = {0,1,2,1,0,2,1,2,1,0,2};
constexpr double FAN_[3] = {3.0, 4.0, 4.0};

struct KTab { float v[9][9][9]; };

constexpr KTab buildK() {
    KTab T{};
    for (int p = 0; p < 11; ++p) {
        const int a = PA_[p], b = PB_[p], c = PC_[p];
        double cgt[5][5] = {};
        for (int i = 0; i < 2*a+1; ++i)
            for (int k = 0; k < 2*b+1; ++k) {
                int m3 = (i-a) + (k-b);
                cgt[i][k] = (m3 >= -c && m3 <= c) ? su2cg(a,b,c,i-a,k-b,m3) : 0.0;
            }
        double R[5][5][5] = {};
        double nrm = 0.0;
        for (int j = 0; j < 2*a+1; ++j)
            for (int l = 0; l < 2*b+1; ++l)
                for (int m = 0; m < 2*c+1; ++m) {
                    double re = 0.0;
                    for (int i = 0; i < 2*a+1; ++i)
                        for (int k = 0; k < 2*b+1; ++k) {
                            double g = cgt[i][k];
                            if (g == 0.0) continue;
                            int n = (i-a) + (k-b) + c;
                            CD t12 = cmul(qent(a,i,j), qent(b,k,l));
                            CD q3  = qent(c,n,m);
                            re += (t12.re*q3.re + t12.im*q3.im) * g;
                        }
                    R[j][l][m] = re;
                    nrm += re*re;
                }
        double sc = csqrt((2.0*c+1.0)/FAN_[c]) / csqrt(nrm);
        for (int j = 0; j < 2*a+1; ++j)
            for (int l = 0; l < 2*b+1; ++l)
                for (int m = 0; m < 2*c+1; ++m)
                    T.v[a*a+j][b*b+l][c*c+m] = (float)(R[j][l][m] * sc);
    }
    return T;
}

constexpr KTab KT = buildK();

constexpr int pathOf(int a, int b, int c) {
    for (int p = 0; p < 11; ++p) if (PA_[p]==a && PB_[p]==b && PC_[p]==c) return p;
    return 0;
}
constexpr bool allowedC(int a, int b, int c) {
    int lo = a > b ? a - b : b - a;
    return c >= lo && c <= a + b && (((a + b + c) & 1) == 0);
}
constexpr bool anyNZ(int i, int j) {
    for (int k = 0; k < 9; ++k) if (KT.v[i][j][k] != 0.0f) return true;
    return false;
}
constexpr bool rowNZ(int a, int b, int c, int dk) {
    for (int di = 0; di < 2*a+1; ++di)
        for (int dj = 0; dj < 2*b+1; ++dj)
            if (KT.v[a*a+di][b*b+dj][c*c+dk] != 0.0f) return true;
    return false;
}

} // namespace cg

// ===========================================================================
// Pipelined coalesced streaming kernel.
// One wave per block owns a 128-item tile; persistent grid-stride loop over
// tiles with double-buffered LDS. global_load_lds prefetch of tile t+1 stays
// in flight across compute of tile t (counted s_waitcnt vmcnt(12), never 0
// in steady state). No __syncthreads anywhere -> no vmcnt(0) drains.
// LDS/block: 2 buf x (x+y) x 4608B = 18,432B + ~900B weights -> 8 blocks/CU.
// ===========================================================================

#define BLK    64
#define TPV    2
#define IPT    (BLK * TPV)        // 128 items per tile
#define SLICEF (IPT * 9)          // 1152 floats per array slice
#define BUFF   (SLICEF * 2)       // x+y floats per buffer
#define NBLOCKS 2048              // 8 per CU

#define GL_LDS16(g, l) __builtin_amdgcn_global_load_lds( \
    (const __attribute__((address_space(1))) void*)(g), \
    (__attribute__((address_space(3))) void*)(l), 16, 0, 0)
#define GL_LDS4(g, l) __builtin_amdgcn_global_load_lds( \
    (const __attribute__((address_space(1))) void*)(g), \
    (__attribute__((address_space(3))) void*)(l), 4, 0, 0)

// stage one tile (12 vmem ops: 8x16B + 4x4B per wave), linear LDS layout
#define STAGE(tt, bb) do { \
    const float* gx_ = x + (tt) * (long)SLICEF; \
    const float* gy_ = y + (tt) * (long)SLICEF; \
    float* lx_ = &lds[(bb) * BUFF]; \
    float* ly_ = lx_ + SLICEF; \
    _Pragma("unroll") \
    for (int q_ = 0; q_ < 4; ++q_) { \
        GL_LDS16(gx_ + q_ * 256 + lane * 4, lx_ + q_ * 256); \
        GL_LDS16(gy_ + q_ * 256 + lane * 4, ly_ + q_ * 256); \
    } \
    _Pragma("unroll") \
    for (int c_ = 0; c_ < 2; ++c_) { \
        GL_LDS4(gx_ + 1024 + c_ * 64 + lane, lx_ + 1024 + c_ * 64); \
        GL_LDS4(gy_ + 1024 + c_ * 64 + lane, ly_ + 1024 + c_ * 64); \
    } \
} while (0)

__global__ __launch_bounds__(BLK) void tp_main_kernel(
        const float* __restrict__ x, const float* __restrict__ y,
        float* __restrict__ out, const float* __restrict__ tpw,
        const float* __restrict__ Wfx, const float* __restrict__ bfx,
        const float* __restrict__ Wfy, const float* __restrict__ bfy,
        long n_items)
{
    __shared__ __align__(16) float lds[2 * BUFF];   // 18,432 B
    __shared__ __align__(16) float Wc[9][24];       // [k][0..8]=Wfx, [12..20]=Wfy
    __shared__ float bs[9];

    const int lane = threadIdx.x;

    // ---- per-wave weight staging (wave-local, in-order DS, no barrier) ----
    #pragma unroll
    for (int u0 = 0; u0 < 2; ++u0) {
        int u = u0 * 64 + lane;
        if (u < 81) { Wc[u / 9][u % 9] = Wfx[u]; Wc[u / 9][12 + u % 9] = Wfy[u]; }
    }
    if (lane < 9) bs[lane] = bfx[lane] + bfy[lane];

    float w[11];
    #pragma unroll
    for (int p = 0; p < 11; ++p) {
        union { float f; int i; } u;
        u.f = tpw[p];
        u.i = __builtin_amdgcn_readfirstlane(u.i);
        w[p] = u.f;
    }

    const long ntiles = n_items / IPT;
    long tile = blockIdx.x;
    int cur = 0;

    if (tile < ntiles) STAGE(tile, 0);

    for (; tile < ntiles; tile += NBLOCKS) {
        const long nxt = tile + NBLOCKS;
        if (nxt < ntiles) {
            STAGE(nxt, cur ^ 1);
            // wait for THIS tile's 12 loads only; next tile's 12 stay in flight
            asm volatile("s_waitcnt vmcnt(12)" ::: "memory");
        } else {
            asm volatile("s_waitcnt vmcnt(0)" ::: "memory");
        }

        float* bx = &lds[cur * BUFF];

        // ---- item-major register load (2 consecutive items per lane) ----
        float xl[18], yl[18];
        {
            const float2* px = reinterpret_cast<const float2*>(bx + lane * 18);
            const float2* py = reinterpret_cast<const float2*>(bx + SLICEF + lane * 18);
            #pragma unroll
            for (int q = 0; q < 9; ++q) {
                float2 a2 = px[q]; xl[2*q] = a2.x; xl[2*q+1] = a2.y;
                float2 b2 = py[q]; yl[2*q] = b2.x; yl[2*q+1] = b2.y;
            }
        }

        // ---- biases ----
        float acc[18];
        #pragma unroll
        for (int k = 0; k < 9; ++k) { float bb = bs[k]; acc[k] = bb; acc[9 + k] = bb; }

        // ---- linear branches ----
        #pragma unroll
        for (int k = 0; k < 9; ++k) {
            float4 wxa = *reinterpret_cast<const float4*>(&Wc[k][0]);
            float4 wxb = *reinterpret_cast<const float4*>(&Wc[k][4]);
            float  wx8 = Wc[k][8];
            float4 wya = *reinterpret_cast<const float4*>(&Wc[k][12]);
            float4 wyb = *reinterpret_cast<const float4*>(&Wc[k][16]);
            float  wy8 = Wc[k][20];
            const float wxr[9] = {wxa.x,wxa.y,wxa.z,wxa.w,wxb.x,wxb.y,wxb.z,wxb.w,wx8};
            const float wyr[9] = {wya.x,wya.y,wya.z,wya.w,wyb.x,wyb.y,wyb.z,wyb.w,wy8};
            float s0 = acc[k], s1 = acc[9 + k];
            #pragma unroll
            for (int i = 0; i < 9; ++i) {
                s0 += wxr[i] * xl[i]     + wyr[i] * yl[i];
                s1 += wxr[i] * xl[9 + i] + wyr[i] * yl[9 + i];
            }
            acc[k] = s0; acc[9 + k] = s1;
        }

        // ---- tensor product: compile-time-folded sparse 3j constants ----
        #pragma unroll
        for (int a = 0; a < 3; ++a) {
            #pragma unroll
            for (int b = 0; b < 3; ++b) {
                float pav[3][5][2];
                #pragma unroll
                for (int c = 0; c < 3; ++c) {
                    if (cg::allowedC(a, b, c)) {
                        #pragma unroll
                        for (int dk = 0; dk < 2 * c + 1; ++dk)
                            if (cg::rowNZ(a, b, c, dk)) { pav[c][dk][0] = 0.f; pav[c][dk][1] = 0.f; }
                    }
                }
                #pragma unroll
                for (int di = 0; di < 2 * a + 1; ++di) {
                    #pragma unroll
                    for (int dj = 0; dj < 2 * b + 1; ++dj) {
                        const int i = a * a + di, j = b * b + dj;
                        if (cg::anyNZ(i, j)) {
                            const float p0 = xl[i]     * yl[j];
                            const float p1 = xl[9 + i] * yl[9 + j];
                            #pragma unroll
                            for (int c = 0; c < 3; ++c) {
                                if (cg::allowedC(a, b, c)) {
                                    #pragma unroll
                                    for (int dk = 0; dk < 2 * c + 1; ++dk) {
                                        const float kv = cg::KT.v[i][j][c * c + dk];
                                        if (kv != 0.0f) {
                                            pav[c][dk][0] += kv * p0;
                                            pav[c][dk][1] += kv * p1;
                                        }
                                    }
                                }
                            }
                        }
                    }
                }
                #pragma unroll
                for (int c = 0; c < 3; ++c) {
                    if (cg::allowedC(a, b, c)) {
                        const int p = cg::pathOf(a, b, c);
                        #pragma unroll
                        for (int dk = 0; dk < 2 * c + 1; ++dk) {
                            if (cg::rowNZ(a, b, c, dk)) {
                                acc[c * c + dk]     += w[p] * pav[c][dk][0];
                                acc[9 + c * c + dk] += w[p] * pav[c][dk][1];
                            }
                        }
                    }
                }
            }
        }

        // ---- restage output into consumed x-slice (wave-local ordering) ----
        {
            float2* po = reinterpret_cast<float2*>(bx + lane * 18);
            #pragma unroll
            for (int q = 0; q < 9; ++q) po[q] = make_float2(acc[2*q], acc[2*q+1]);
        }

        // ---- coalesced float2 stores (9 vmem ops) ----
        {
            float2* og = reinterpret_cast<float2*>(out) + tile * (SLICEF / 2);
            const float2* ps = reinterpret_cast<const float2*>(bx);
            #pragma unroll
            for (int q = 0; q < 9; ++q) og[q * 64 + lane] = ps[q * 64 + lane];
        }

        cur ^= 1;
    }
}

// ===========================================================================

extern "C" void kernel_launch(void* const* d_in, const int* in_sizes, int n_in,
                              void* d_out, int out_size, void* d_ws, size_t ws_size,
                              hipStream_t stream) {
    const float* x   = (const float*)d_in[0];
    const float* y   = (const float*)d_in[1];
    const float* tpw = (const float*)d_in[2];
    const float* Wfx = (const float*)d_in[3];
    const float* bfx = (const float*)d_in[4];
    const float* Wfy = (const float*)d_in[5];
    const float* bfy = (const float*)d_in[6];
    float* out = (float*)d_out;

    long n_items = (long)out_size / 9;   // 16,777,216 (multiple of 128)

    hipLaunchKernelGGL(tp_main_kernel, dim3(NBLOCKS), dim3(BLK), 0, stream,
                       x, y, out, tpw, Wfx, bfx, Wfy, bfy, n_items);
}

// Round 7
// 3157.452 us; speedup vs baseline: 1.1149x; 1.1149x over previous
//
#include <hip/hip_runtime.h>

// ===========================================================================
// Compile-time construction of the e3nn real Wigner-3j path tensor.
// (numerically validated rounds 3-6: absmax 0.031 vs threshold 0.259)
// ===========================================================================
namespace cg {

constexpr double csqrt(double x) {
    double g = x < 1.0 ? 1.0 : x;
    for (int i = 0; i < 64; ++i) g = 0.5 * (g + x / g);
    return g;
}
constexpr double fact(int n) { double r = 1.0; for (int i = 2; i <= n; ++i) r *= (double)i; return r; }

constexpr double su2cg(int j1, int j2, int j3, int m1, int m2, int m3) {
    if (m1 + m2 != m3) return 0.0;
    double pre = csqrt((2.0*j3+1.0)*fact(j3+j1-j2)*fact(j3-j1+j2)*fact(j1+j2-j3)
                       *fact(j3+m3)*fact(j3-m3)
                       /(fact(j1+j2+j3+1)*fact(j1-m1)*fact(j1+m1)*fact(j2-m2)*fact(j2+m2)));
    double S = 0.0;
    for (int v = 0; v <= j1 + j2 + j3; ++v) {
        int b1 = j3-j1+j2-v, b2 = j3+m3-v, b3 = v+j1-j2-m3, b4 = j2+j3+m1-v, b5 = j1-m1+v;
        if (b1 < 0 || b2 < 0 || b3 < 0 || b4 < 0 || b5 < 0) continue;
        double term = fact(b4)*fact(b5)/(fact(v)*fact(b1)*fact(b2)*fact(b3));
        S += ((v + j2 + m2) & 1) ? -term : term;
    }
    return pre * S;
}

struct CD { double re, im; };
constexpr CD cmul(CD a, CD b) { return { a.re*b.re - a.im*b.im, a.re*b.im + a.im*b.re }; }

constexpr CD qent(int l, int r, int c) {
    const double s = 0.70710678118654752440;
    CD v{0.0, 0.0};
    int m = r - l;
    if (m < 0)       { if (c == l - m) v = { s, 0.0 }; else if (c == l + m) v = { 0.0, -s }; }
    else if (m == 0) { if (c == l)     v = { 1.0, 0.0 }; }
    else             { double sg = (m & 1) ? -1.0 : 1.0;
                       if (c == l + m) v = { sg*s, 0.0 }; else if (c == l - m) v = { 0.0, sg*s }; }
    if      (l == 1) v = { v.im, -v.re };
    else if (l == 2) v = { -v.re, -v.im };
    return v;
}

constexpr int PA_[11] = {0,0,0,1,1,1,1,2,2,2,2};
constexpr int PB_[11] = {0,1,2,0,1,1,2,0,1,2,2};
constexpr int PC_[11] = {0,1,2,1,0,2,1,2,1,0,2};
constexpr double FAN_[3] = {3.0, 4.0, 4.0};

struct KTab { float v[9][9][9]; };

constexpr KTab buildK() {
    KTab T{};
    for (int p = 0; p < 11; ++p) {
        const int a = PA_[p], b = PB_[p], c = PC_[p];
        double cgt[5][5] = {};
        for (int i = 0; i < 2*a+1; ++i)
            for (int k = 0; k < 2*b+1; ++k) {
                int m3 = (i-a) + (k-b);
                cgt[i][k] = (m3 >= -c && m3 <= c) ? su2cg(a,b,c,i-a,k-b,m3) : 0.0;
            }
        double R[5][5][5] = {};
        double nrm = 0.0;
        for (int j = 0; j < 2*a+1; ++j)
            for (int l = 0; l < 2*b+1; ++l)
                for (int m = 0; m < 2*c+1; ++m) {
                    double re = 0.0;
                    for (int i = 0; i < 2*a+1; ++i)
                        for (int k = 0; k < 2*b+1; ++k) {
                            double g = cgt[i][k];
                            if (g == 0.0) continue;
                            int n = (i-a) + (k-b) + c;
                            CD t12 = cmul(qent(a,i,j), qent(b,k,l));
                            CD q3  = qent(c,n,m);
                            re += (t12.re*q3.re + t12.im*q3.im) * g;
                        }
                    R[j][l][m] = re;
                    nrm += re*re;
                }
        double sc = csqrt((2.0*c+1.0)/FAN_[c]) / csqrt(nrm);
        for (int j = 0; j < 2*a+1; ++j)
            for (int l = 0; l < 2*b+1; ++l)
                for (int m = 0; m < 2*c+1; ++m)
                    T.v[a*a+j][b*b+l][c*c+m] = (float)(R[j][l][m] * sc);
    }
    return T;
}

constexpr KTab KT = buildK();

constexpr int pathOf(int a, int b, int c) {
    for (int p = 0; p < 11; ++p) if (PA_[p]==a && PB_[p]==b && PC_[p]==c) return p;
    return 0;
}
constexpr bool allowedC(int a, int b, int c) {
    int lo = a > b ? a - b : b - a;
    return c >= lo && c <= a + b && (((a + b + c) & 1) == 0);
}
constexpr bool anyNZ(int i, int j) {
    for (int k = 0; k < 9; ++k) if (KT.v[i][j][k] != 0.0f) return true;
    return false;
}
constexpr bool rowNZ(int a, int b, int c, int dk) {
    for (int di = 0; di < 2*a+1; ++di)
        for (int dj = 0; dj < 2*b+1; ++dj)
            if (KT.v[a*a+di][b*b+dj][c*c+dk] != 0.0f) return true;
    return false;
}

} // namespace cg

// ===========================================================================
// Round 7: coalesced register staging + wave-private LDS transpose + pk-f32.
//   - each WAVE owns a contiguous 128-item (4608 B) slice per tile
//   - 9+9 coalesced float2 loads -> REGISTERS (precise counted waitcnts)
//   - registers -> wave-private LDS (linear), read back item-major (stride 9
//     words: 9 coprime 32 -> bank-conflict-free); NO barriers anywhere
//   - item pair packed into float2 ext-vector -> v_pk_fma_f32 math
//   - tile t+1 loads issued before tile t compute (latency hidden in regs)
// LDS: 4 waves x 9216 B + weights ~= 37.8 KB -> 4 blocks/CU = 16 waves/CU.
// ===========================================================================

#define BLK     256
#define NT      8               // tiles per block
#define WSLICE  1152            // floats per wave slice (128 items x 9)
#define BFLOATS (4 * WSLICE)    // 4608 floats per block-tile (512 items)

typedef float f2 __attribute__((ext_vector_type(2)));
typedef float f4 __attribute__((ext_vector_type(4)));

__global__ __launch_bounds__(BLK) void tp_main_kernel(
        const float* __restrict__ x, const float* __restrict__ y,
        float* __restrict__ out, const float* __restrict__ tpw,
        const float* __restrict__ Wfx, const float* __restrict__ bfx,
        const float* __restrict__ Wfy, const float* __restrict__ bfy,
        long n_items)
{
    __shared__ __align__(16) float lds[4][2 * WSLICE];   // per-wave x | y
    __shared__ __align__(16) float Wx[9][12];            // padded rows (48 B)
    __shared__ __align__(16) float Wy[9][12];
    __shared__ float bs[9];

    const int t    = threadIdx.x;
    const int w    = t >> 6;
    const int lane = t & 63;

    // ---- wave-redundant weight staging (no barrier needed) ----
    #pragma unroll
    for (int u0 = 0; u0 < 2; ++u0) {
        int u = u0 * 64 + lane;
        if (u < 81) { Wx[u / 9][u % 9] = Wfx[u]; Wy[u / 9][u % 9] = Wfy[u]; }
    }
    if (lane < 9) bs[lane] = bfx[lane] + bfy[lane];

    float pw[11];
    #pragma unroll
    for (int p = 0; p < 11; ++p) {
        union { float f; int i; } u;
        u.f = tpw[p];
        u.i = __builtin_amdgcn_readfirstlane(u.i);
        pw[p] = u.f;
    }

    float* const L = lds[w];

    const long tile0 = (long)blockIdx.x * NT;
    const long ntile = n_items / 512;          // block-tiles total
    if (tile0 >= ntile) return;

    // float offsets: tile tt, wave w, lane -> (tt*512 + w*128)*9 + lane*2
    const float* xp = x   + tile0 * BFLOATS + w * WSLICE + lane * 2;
    const float* yp = y   + tile0 * BFLOATS + w * WSLICE + lane * 2;
    float*       op = out + tile0 * BFLOATS + w * WSLICE + lane * 2;

    f2 ldx[9], ldy[9];

    // ---- prologue: load + stage tile 0 ----
    #pragma unroll
    for (int q = 0; q < 9; ++q) {
        ldx[q] = *reinterpret_cast<const f2*>(xp + q * 128);
        ldy[q] = *reinterpret_cast<const f2*>(yp + q * 128);
    }
    #pragma unroll
    for (int q = 0; q < 9; ++q) {
        *reinterpret_cast<f2*>(&L[q * 128 + lane * 2])          = ldx[q];
        *reinterpret_cast<f2*>(&L[WSLICE + q * 128 + lane * 2]) = ldy[q];
    }

    const int nt = (int)((ntile - tile0) < NT ? (ntile - tile0) : NT);

    for (int tt = 0; tt < nt; ++tt) {
        // ---- prefetch tile tt+1 into registers (in flight across compute) ----
        const bool have_next = (tt + 1) < nt;
        if (have_next) {
            xp += BFLOATS; yp += BFLOATS;
            #pragma unroll
            for (int q = 0; q < 9; ++q) {
                ldx[q] = *reinterpret_cast<const f2*>(xp + q * 128);
                ldy[q] = *reinterpret_cast<const f2*>(yp + q * 128);
            }
        }

        // ---- transpose read: item pair (2k, 2k+1) packed into f2 lanes ----
        const int tb = lane * 18;
        f2 xl[9], yl[9];
        #pragma unroll
        for (int i = 0; i < 9; ++i) {
            xl[i] = f2{ L[tb + i], L[tb + 9 + i] };
            yl[i] = f2{ L[WSLICE + tb + i], L[WSLICE + tb + 9 + i] };
        }

        // ---- biases ----
        f2 acc[9];
        #pragma unroll
        for (int k = 0; k < 9; ++k) { float bb = bs[k]; acc[k] = f2{ bb, bb }; }

        // ---- linear branches (weights per-row as b128 reads) ----
        #pragma unroll
        for (int k = 0; k < 9; ++k) {
            f4 wxa = *reinterpret_cast<const f4*>(&Wx[k][0]);
            f4 wxb = *reinterpret_cast<const f4*>(&Wx[k][4]);
            float wx8 = Wx[k][8];
            f4 wya = *reinterpret_cast<const f4*>(&Wy[k][0]);
            f4 wyb = *reinterpret_cast<const f4*>(&Wy[k][4]);
            float wy8 = Wy[k][8];
            f2 s = acc[k];
            #pragma unroll
            for (int i = 0; i < 4; ++i) {
                s += xl[i] * wxa[i];     s += yl[i] * wya[i];
                s += xl[4 + i] * wxb[i]; s += yl[4 + i] * wyb[i];
            }
            s += xl[8] * wx8; s += yl[8] * wy8;
            acc[k] = s;
        }

        // ---- tensor product: compile-time sparse 3j, pk-packed pair ----
        #pragma unroll
        for (int a = 0; a < 3; ++a) {
            #pragma unroll
            for (int b = 0; b < 3; ++b) {
                f2 pav[3][5];
                #pragma unroll
                for (int c = 0; c < 3; ++c) {
                    if (cg::allowedC(a, b, c)) {
                        #pragma unroll
                        for (int dk = 0; dk < 2 * c + 1; ++dk)
                            if (cg::rowNZ(a, b, c, dk)) pav[c][dk] = f2{ 0.f, 0.f };
                    }
                }
                #pragma unroll
                for (int di = 0; di < 2 * a + 1; ++di) {
                    #pragma unroll
                    for (int dj = 0; dj < 2 * b + 1; ++dj) {
                        const int i = a * a + di, j = b * b + dj;
                        if (cg::anyNZ(i, j)) {
                            const f2 p = xl[i] * yl[j];
                            #pragma unroll
                            for (int c = 0; c < 3; ++c) {
                                if (cg::allowedC(a, b, c)) {
                                    #pragma unroll
                                    for (int dk = 0; dk < 2 * c + 1; ++dk) {
                                        const float kv = cg::KT.v[i][j][c * c + dk];
                                        if (kv != 0.0f) pav[c][dk] += p * kv;
                                    }
                                }
                            }
                        }
                    }
                }
                #pragma unroll
                for (int c = 0; c < 3; ++c) {
                    if (cg::allowedC(a, b, c)) {
                        const int p = cg::pathOf(a, b, c);
                        #pragma unroll
                        for (int dk = 0; dk < 2 * c + 1; ++dk)
                            if (cg::rowNZ(a, b, c, dk))
                                acc[c * c + dk] += pav[c][dk] * pw[p];
                    }
                }
            }
        }

        // ---- transpose out through x-region, coalesced store ----
        #pragma unroll
        for (int i = 0; i < 9; ++i) { L[tb + i] = acc[i][0]; L[tb + 9 + i] = acc[i][1]; }
        #pragma unroll
        for (int q = 0; q < 9; ++q)
            *reinterpret_cast<f2*>(op + q * 128) =
                *reinterpret_cast<const f2*>(&L[q * 128 + lane * 2]);
        op += BFLOATS;

        // ---- stage tile tt+1 (loads have had the whole compute to land) ----
        if (have_next) {
            #pragma unroll
            for (int q = 0; q < 9; ++q) {
                *reinterpret_cast<f2*>(&L[q * 128 + lane * 2])          = ldx[q];
                *reinterpret_cast<f2*>(&L[WSLICE + q * 128 + lane * 2]) = ldy[q];
            }
        }
    }
}

// ===========================================================================

extern "C" void kernel_launch(void* const* d_in, const int* in_sizes, int n_in,
                              void* d_out, int out_size, void* d_ws, size_t ws_size,
                              hipStream_t stream) {
    const float* x   = (const float*)d_in[0];
    const float* y   = (const float*)d_in[1];
    const float* tpw = (const float*)d_in[2];
    const float* Wfx = (const float*)d_in[3];
    const float* bfx = (const float*)d_in[4];
    const float* Wfy = (const float*)d_in[5];
    const float* bfy = (const float*)d_in[6];
    float* out = (float*)d_out;

    long n_items = (long)out_size / 9;                  // 16,777,216
    long ntile = n_items / 512;                         // 32,768 block-tiles
    long grid = (ntile + NT - 1) / NT;                  // 4,096 blocks

    hipLaunchKernelGGL(tp_main_kernel, dim3((unsigned)grid), dim3(BLK), 0, stream,
                       x, y, out, tpw, Wfx, bfx, Wfy, bfy, n_items);
}

// Round 8
// 2890.805 us; speedup vs baseline: 1.2178x; 1.0922x over previous
//
#include <hip/hip_runtime.h>

// ===========================================================================
// Compile-time construction of the e3nn real Wigner-3j path tensor.
// (numerically validated rounds 3-7: absmax 0.031 vs threshold 0.259)
// ===========================================================================
namespace cg {

constexpr double csqrt(double x) {
    double g = x < 1.0 ? 1.0 : x;
    for (int i = 0; i < 64; ++i) g = 0.5 * (g + x / g);
    return g;
}
constexpr double fact(int n) { double r = 1.0; for (int i = 2; i <= n; ++i) r *= (double)i; return r; }

constexpr double su2cg(int j1, int j2, int j3, int m1, int m2, int m3) {
    if (m1 + m2 != m3) return 0.0;
    double pre = csqrt((2.0*j3+1.0)*fact(j3+j1-j2)*fact(j3-j1+j2)*fact(j1+j2-j3)
                       *fact(j3+m3)*fact(j3-m3)
                       /(fact(j1+j2+j3+1)*fact(j1-m1)*fact(j1+m1)*fact(j2-m2)*fact(j2+m2)));
    double S = 0.0;
    for (int v = 0; v <= j1 + j2 + j3; ++v) {
        int b1 = j3-j1+j2-v, b2 = j3+m3-v, b3 = v+j1-j2-m3, b4 = j2+j3+m1-v, b5 = j1-m1+v;
        if (b1 < 0 || b2 < 0 || b3 < 0 || b4 < 0 || b5 < 0) continue;
        double term = fact(b4)*fact(b5)/(fact(v)*fact(b1)*fact(b2)*fact(b3));
        S += ((v + j2 + m2) & 1) ? -term : term;
    }
    return pre * S;
}

struct CD { double re, im; };
constexpr CD cmul(CD a, CD b) { return { a.re*b.re - a.im*b.im, a.re*b.im + a.im*b.re }; }

constexpr CD qent(int l, int r, int c) {
    const double s = 0.70710678118654752440;
    CD v{0.0, 0.0};
    int m = r - l;
    if (m < 0)       { if (c == l - m) v = { s, 0.0 }; else if (c == l + m) v = { 0.0, -s }; }
    else if (m == 0) { if (c == l)     v = { 1.0, 0.0 }; }
    else             { double sg = (m & 1) ? -1.0 : 1.0;
                       if (c == l + m) v = { sg*s, 0.0 }; else if (c == l - m) v = { 0.0, sg*s }; }
    if      (l == 1) v = { v.im, -v.re };
    else if (l == 2) v = { -v.re, -v.im };
    return v;
}

constexpr int PA_[11] = {0,0,0,1,1,1,1,2,2,2,2};
constexpr int PB_[11] = {0,1,2,0,1,1,2,0,1,2,2};
constexpr int PC_[11] = {0,1,2,1,0,2,1,2,1,0,2};
constexpr double FAN_[3] = {3.0, 4.0, 4.0};

struct KTab { float v[9][9][9]; };

constexpr KTab buildK() {
    KTab T{};
    for (int p = 0; p < 11; ++p) {
        const int a = PA_[p], b = PB_[p], c = PC_[p];
        double cgt[5][5] = {};
        for (int i = 0; i < 2*a+1; ++i)
            for (int k = 0; k < 2*b+1; ++k) {
                int m3 = (i-a) + (k-b);
                cgt[i][k] = (m3 >= -c && m3 <= c) ? su2cg(a,b,c,i-a,k-b,m3) : 0.0;
            }
        double R[5][5][5] = {};
        double nrm = 0.0;
        for (int j = 0; j < 2*a+1; ++j)
            for (int l = 0; l < 2*b+1; ++l)
                for (int m = 0; m < 2*c+1; ++m) {
                    double re = 0.0;
                    for (int i = 0; i < 2*a+1; ++i)
                        for (int k = 0; k < 2*b+1; ++k) {
                            double g = cgt[i][k];
                            if (g == 0.0) continue;
                            int n = (i-a) + (k-b) + c;
                            CD t12 = cmul(qent(a,i,j), qent(b,k,l));
                            CD q3  = qent(c,n,m);
                            re += (t12.re*q3.re + t12.im*q3.im) * g;
                        }
                    R[j][l][m] = re;
                    nrm += re*re;
                }
        double sc = csqrt((2.0*c+1.0)/FAN_[c]) / csqrt(nrm);
        for (int j = 0; j < 2*a+1; ++j)
            for (int l = 0; l < 2*b+1; ++l)
                for (int m = 0; m < 2*c+1; ++m)
                    T.v[a*a+j][b*b+l][c*c+m] = (float)(R[j][l][m] * sc);
    }
    return T;
}

constexpr KTab KT = buildK();

constexpr int pathOf(int a, int b, int c) {
    for (int p = 0; p < 11; ++p) if (PA_[p]==a && PB_[p]==b && PC_[p]==c) return p;
    return 0;
}
constexpr bool allowedC(int a, int b, int c) {
    int lo = a > b ? a - b : b - a;
    return c >= lo && c <= a + b && (((a + b + c) & 1) == 0);
}
constexpr bool anyNZ(int i, int j) {
    for (int k = 0; k < 9; ++k) if (KT.v[i][j][k] != 0.0f) return true;
    return false;
}
constexpr bool rowNZ(int a, int b, int c, int dk) {
    for (int di = 0; di < 2*a+1; ++di)
        for (int dj = 0; dj < 2*b+1; ++dj)
            if (KT.v[a*a+di][b*b+dj][c*c+dk] != 0.0f) return true;
    return false;
}

} // namespace cg

// ===========================================================================
// Round 8: R1's exact structure (best known, 1028us) with ONE change:
// C tensor folded to compile-time constants (deletes 363 ds_reads/quad),
// plus b128 W-row reads (162 -> 54 ds_reads/quad).
// TPV=4, float4 strided direct loads/stores, 256-thread blocks, grid 16384.
// ===========================================================================

#define BLK 256
#define TPV 4

typedef float f4 __attribute__((ext_vector_type(4)));

__global__ __launch_bounds__(BLK) void tp_main_kernel(
        const float* __restrict__ x, const float* __restrict__ y,
        float* __restrict__ out, const float* __restrict__ tpw,
        const float* __restrict__ Wfx, const float* __restrict__ bfx,
        const float* __restrict__ Wfy, const float* __restrict__ bfy)
{
    __shared__ __align__(16) float Wx[9][12];   // padded rows (48 B)
    __shared__ __align__(16) float Wy[9][12];
    __shared__ float bs[9];

    const int t = threadIdx.x;

    if (t < 81) { Wx[t / 9][t % 9] = Wfx[t]; Wy[t / 9][t % 9] = Wfy[t]; }
    if (t < 9)  bs[t] = bfx[t] + bfy[t];

    float w[11];
    #pragma unroll
    for (int p = 0; p < 11; ++p) {
        union { float f; int i; } u;
        u.f = tpw[p];
        u.i = __builtin_amdgcn_readfirstlane(u.i);
        w[p] = u.f;
    }

    __syncthreads();

    const long set = (long)blockIdx.x * BLK + t;   // grid covers exactly

    const f4* xg = reinterpret_cast<const f4*>(x) + set * 9;
    const f4* yg = reinterpret_cast<const f4*>(y) + set * 9;

    __align__(16) float xs[36], ys[36];   // [v*9 + comp]
    #pragma unroll
    for (int q = 0; q < 9; ++q) {
        *reinterpret_cast<f4*>(&xs[q * 4]) = xg[q];
        *reinterpret_cast<f4*>(&ys[q * 4]) = yg[q];
    }

    // ---- biases ----
    float acc[36];
    #pragma unroll
    for (int k = 0; k < 9; ++k) {
        float bb = bs[k];
        #pragma unroll
        for (int v = 0; v < TPV; ++v) acc[v * 9 + k] = bb;
    }

    // ---- linear branches (b128 row reads) ----
    #pragma unroll
    for (int k = 0; k < 9; ++k) {
        f4 wxa = *reinterpret_cast<const f4*>(&Wx[k][0]);
        f4 wxb = *reinterpret_cast<const f4*>(&Wx[k][4]);
        float wx8 = Wx[k][8];
        f4 wya = *reinterpret_cast<const f4*>(&Wy[k][0]);
        f4 wyb = *reinterpret_cast<const f4*>(&Wy[k][4]);
        float wy8 = Wy[k][8];
        const float wxr[9] = {wxa.x,wxa.y,wxa.z,wxa.w,wxb.x,wxb.y,wxb.z,wxb.w,wx8};
        const float wyr[9] = {wya.x,wya.y,wya.z,wya.w,wyb.x,wyb.y,wyb.z,wyb.w,wy8};
        #pragma unroll
        for (int v = 0; v < TPV; ++v) {
            float s = acc[v * 9 + k];
            #pragma unroll
            for (int i = 0; i < 9; ++i)
                s += wxr[i] * xs[v * 9 + i] + wyr[i] * ys[v * 9 + i];
            acc[v * 9 + k] = s;
        }
    }

    // ---- tensor product: compile-time sparse 3j (literal-operand fmac) ----
    #pragma unroll
    for (int a = 0; a < 3; ++a) {
        #pragma unroll
        for (int b = 0; b < 3; ++b) {
            float pav[3][5][TPV];
            #pragma unroll
            for (int c = 0; c < 3; ++c) {
                if (cg::allowedC(a, b, c)) {
                    #pragma unroll
                    for (int dk = 0; dk < 2 * c + 1; ++dk)
                        if (cg::rowNZ(a, b, c, dk)) {
                            #pragma unroll
                            for (int v = 0; v < TPV; ++v) pav[c][dk][v] = 0.f;
                        }
                }
            }
            #pragma unroll
            for (int di = 0; di < 2 * a + 1; ++di) {
                #pragma unroll
                for (int dj = 0; dj < 2 * b + 1; ++dj) {
                    const int i = a * a + di, j = b * b + dj;
                    if (cg::anyNZ(i, j)) {
                        float p[TPV];
                        #pragma unroll
                        for (int v = 0; v < TPV; ++v) p[v] = xs[v * 9 + i] * ys[v * 9 + j];
                        #pragma unroll
                        for (int c = 0; c < 3; ++c) {
                            if (cg::allowedC(a, b, c)) {
                                #pragma unroll
                                for (int dk = 0; dk < 2 * c + 1; ++dk) {
                                    const float kv = cg::KT.v[i][j][c * c + dk];
                                    if (kv != 0.0f) {
                                        #pragma unroll
                                        for (int v = 0; v < TPV; ++v)
                                            pav[c][dk][v] += kv * p[v];
                                    }
                                }
                            }
                        }
                    }
                }
            }
            #pragma unroll
            for (int c = 0; c < 3; ++c) {
                if (cg::allowedC(a, b, c)) {
                    const int p = cg::pathOf(a, b, c);
                    #pragma unroll
                    for (int dk = 0; dk < 2 * c + 1; ++dk) {
                        if (cg::rowNZ(a, b, c, dk)) {
                            #pragma unroll
                            for (int v = 0; v < TPV; ++v)
                                acc[v * 9 + c * c + dk] += w[p] * pav[c][dk][v];
                        }
                    }
                }
            }
        }
    }

    // ---- direct strided float4 stores ----
    f4* og = reinterpret_cast<f4*>(out) + set * 9;
    #pragma unroll
    for (int q = 0; q < 9; ++q)
        og[q] = *reinterpret_cast<const f4*>(&acc[q * 4]);
}

// ===========================================================================

extern "C" void kernel_launch(void* const* d_in, const int* in_sizes, int n_in,
                              void* d_out, int out_size, void* d_ws, size_t ws_size,
                              hipStream_t stream) {
    const float* x   = (const float*)d_in[0];
    const float* y   = (const float*)d_in[1];
    const float* tpw = (const float*)d_in[2];
    const float* Wfx = (const float*)d_in[3];
    const float* bfx = (const float*)d_in[4];
    const float* Wfy = (const float*)d_in[5];
    const float* bfy = (const float*)d_in[6];
    float* out = (float*)d_out;

    long n_items = (long)out_size / 9;              // 16,777,216
    long n_sets = n_items / TPV;                    // 4,194,304
    long grid = n_sets / BLK;                       // 16,384 (exact)

    hipLaunchKernelGGL(tp_main_kernel, dim3((unsigned)grid), dim3(BLK), 0, stream,
                       x, y, out, tpw, Wfx, bfx, Wfy, bfy);
}

// Round 9
// 554.989 us; speedup vs baseline: 6.3431x; 5.2088x over previous
//
#include <hip/hip_runtime.h>

// ===========================================================================
// Compile-time construction of the e3nn real Wigner-3j path tensor.
// (numerically validated rounds 3-8: absmax 0.031 vs threshold 0.259)
// ===========================================================================
namespace cg {

constexpr double csqrt(double x) {
    double g = x < 1.0 ? 1.0 : x;
    for (int i = 0; i < 64; ++i) g = 0.5 * (g + x / g);
    return g;
}
constexpr double fact(int n) { double r = 1.0; for (int i = 2; i <= n; ++i) r *= (double)i; return r; }

constexpr double su2cg(int j1, int j2, int j3, int m1, int m2, int m3) {
    if (m1 + m2 != m3) return 0.0;
    double pre = csqrt((2.0*j3+1.0)*fact(j3+j1-j2)*fact(j3-j1+j2)*fact(j1+j2-j3)
                       *fact(j3+m3)*fact(j3-m3)
                       /(fact(j1+j2+j3+1)*fact(j1-m1)*fact(j1+m1)*fact(j2-m2)*fact(j2+m2)));
    double S = 0.0;
    for (int v = 0; v <= j1 + j2 + j3; ++v) {
        int b1 = j3-j1+j2-v, b2 = j3+m3-v, b3 = v+j1-j2-m3, b4 = j2+j3+m1-v, b5 = j1-m1+v;
        if (b1 < 0 || b2 < 0 || b3 < 0 || b4 < 0 || b5 < 0) continue;
        double term = fact(b4)*fact(b5)/(fact(v)*fact(b1)*fact(b2)*fact(b3));
        S += ((v + j2 + m2) & 1) ? -term : term;
    }
    return pre * S;
}

struct CD { double re, im; };
constexpr CD cmul(CD a, CD b) { return { a.re*b.re - a.im*b.im, a.re*b.im + a.im*b.re }; }

constexpr CD qent(int l, int r, int c) {
    const double s = 0.70710678118654752440;
    CD v{0.0, 0.0};
    int m = r - l;
    if (m < 0)       { if (c == l - m) v = { s, 0.0 }; else if (c == l + m) v = { 0.0, -s }; }
    else if (m == 0) { if (c == l)     v = { 1.0, 0.0 }; }
    else             { double sg = (m & 1) ? -1.0 : 1.0;
                       if (c == l + m) v = { sg*s, 0.0 }; else if (c == l - m) v = { 0.0, sg*s }; }
    if      (l == 1) v = { v.im, -v.re };
    else if (l == 2) v = { -v.re, -v.im };
    return v;
}

constexpr int PA_[11] = {0,0,0,1,1,1,1,2,2,2,2};
constexpr int PB_[11] = {0,1,2,0,1,1,2,0,1,2,2};
constexpr int PC_[11] = {0,1,2,1,0,2,1,2,1,0,2};
constexpr double FAN_[3] = {3.0, 4.0, 4.0};

struct KTab { float v[9][9][9]; };

constexpr KTab buildK() {
    KTab T{};
    for (int p = 0; p < 11; ++p) {
        const int a = PA_[p], b = PB_[p], c = PC_[p];
        double cgt[5][5] = {};
        for (int i = 0; i < 2*a+1; ++i)
            for (int k = 0; k < 2*b+1; ++k) {
                int m3 = (i-a) + (k-b);
                cgt[i][k] = (m3 >= -c && m3 <= c) ? su2cg(a,b,c,i-a,k-b,m3) : 0.0;
            }
        double R[5][5][5] = {};
        double nrm = 0.0;
        for (int j = 0; j < 2*a+1; ++j)
            for (int l = 0; l < 2*b+1; ++l)
                for (int m = 0; m < 2*c+1; ++m) {
                    double re = 0.0;
                    for (int i = 0; i < 2*a+1; ++i)
                        for (int k = 0; k < 2*b+1; ++k) {
                            double g = cgt[i][k];
                            if (g == 0.0) continue;
                            int n = (i-a) + (k-b) + c;
                            CD t12 = cmul(qent(a,i,j), qent(b,k,l));
                            CD q3  = qent(c,n,m);
                            re += (t12.re*q3.re + t12.im*q3.im) * g;
                        }
                    R[j][l][m] = re;
                    nrm += re*re;
                }
        double sc = csqrt((2.0*c+1.0)/FAN_[c]) / csqrt(nrm);
        for (int j = 0; j < 2*a+1; ++j)
            for (int l = 0; l < 2*b+1; ++l)
                for (int m = 0; m < 2*c+1; ++m)
                    T.v[a*a+j][b*b+l][c*c+m] = (float)(R[j][l][m] * sc);
    }
    return T;
}

constexpr KTab KT = buildK();

// any nonzero K for pair (i,j) within path p's c-block?
constexpr bool pairNZ(int p, int di, int dj) {
    const int a = PA_[p], b = PB_[p], c = PC_[p];
    for (int dk = 0; dk < 2 * c + 1; ++dk)
        if (KT.v[a*a+di][b*b+dj][c*c+dk] != 0.0f) return true;
    return false;
}
constexpr bool rowNZp(int p, int dk) {
    const int a = PA_[p], b = PB_[p], c = PC_[p];
    for (int di = 0; di < 2*a+1; ++di)
        for (int dj = 0; dj < 2*b+1; ++dj)
            if (KT.v[a*a+di][b*b+dj][c*c+dk] != 0.0f) return true;
    return false;
}

} // namespace cg

// ===========================================================================
// Round 9: R8 minus the spill. Path-sequential tensor product keeps peak
// live state at xs+ys+acc (108) + pv (<=20) -> ~150 VGPR, zero scratch.
// TPV=4, float4 strided direct loads/stores, 256-thread blocks, grid 16384.
// ===========================================================================

#define BLK 256
#define TPV 4

typedef float f4 __attribute__((ext_vector_type(4)));

__global__ __launch_bounds__(BLK) void tp_main_kernel(
        const float* __restrict__ x, const float* __restrict__ y,
        float* __restrict__ out, const float* __restrict__ tpw,
        const float* __restrict__ Wfx, const float* __restrict__ bfx,
        const float* __restrict__ Wfy, const float* __restrict__ bfy)
{
    __shared__ __align__(16) float Wx[9][12];   // padded rows (48 B)
    __shared__ __align__(16) float Wy[9][12];
    __shared__ float bs[9];

    const int t = threadIdx.x;

    if (t < 81) { Wx[t / 9][t % 9] = Wfx[t]; Wy[t / 9][t % 9] = Wfy[t]; }
    if (t < 9)  bs[t] = bfx[t] + bfy[t];

    float w[11];
    #pragma unroll
    for (int p = 0; p < 11; ++p) {
        union { float f; int i; } u;
        u.f = tpw[p];
        u.i = __builtin_amdgcn_readfirstlane(u.i);
        w[p] = u.f;
    }

    __syncthreads();

    const long set = (long)blockIdx.x * BLK + t;   // grid covers exactly

    const f4* xg = reinterpret_cast<const f4*>(x) + set * 9;
    const f4* yg = reinterpret_cast<const f4*>(y) + set * 9;

    __align__(16) float xs[36], ys[36];   // [v*9 + comp]
    #pragma unroll
    for (int q = 0; q < 9; ++q) {
        *reinterpret_cast<f4*>(&xs[q * 4]) = xg[q];
        *reinterpret_cast<f4*>(&ys[q * 4]) = yg[q];
    }

    // ---- biases ----
    float acc[36];
    #pragma unroll
    for (int k = 0; k < 9; ++k) {
        float bb = bs[k];
        #pragma unroll
        for (int v = 0; v < TPV; ++v) acc[v * 9 + k] = bb;
    }

    // ---- linear branches (b128 row reads, one row live at a time) ----
    #pragma unroll
    for (int k = 0; k < 9; ++k) {
        f4 wxa = *reinterpret_cast<const f4*>(&Wx[k][0]);
        f4 wxb = *reinterpret_cast<const f4*>(&Wx[k][4]);
        float wx8 = Wx[k][8];
        f4 wya = *reinterpret_cast<const f4*>(&Wy[k][0]);
        f4 wyb = *reinterpret_cast<const f4*>(&Wy[k][4]);
        float wy8 = Wy[k][8];
        #pragma unroll
        for (int v = 0; v < TPV; ++v) {
            float s = acc[v * 9 + k];
            #pragma unroll
            for (int i = 0; i < 4; ++i) {
                s += wxa[i] * xs[v * 9 + i]     + wya[i] * ys[v * 9 + i];
                s += wxb[i] * xs[v * 9 + 4 + i] + wyb[i] * ys[v * 9 + 4 + i];
            }
            s += wx8 * xs[v * 9 + 8] + wy8 * ys[v * 9 + 8];
            acc[v * 9 + k] = s;
        }
    }

    // ---- tensor product: PATH-SEQUENTIAL (peak live pv <= 5*TPV floats) ----
    #pragma unroll
    for (int p = 0; p < 11; ++p) {
        const int a = cg::PA_[p], b = cg::PB_[p], c = cg::PC_[p];
        float pv[5][TPV];
        #pragma unroll
        for (int dk = 0; dk < 2 * c + 1; ++dk) {
            if (cg::rowNZp(p, dk)) {
                #pragma unroll
                for (int v = 0; v < TPV; ++v) pv[dk][v] = 0.f;
            }
        }
        #pragma unroll
        for (int di = 0; di < 2 * a + 1; ++di) {
            #pragma unroll
            for (int dj = 0; dj < 2 * b + 1; ++dj) {
                if (cg::pairNZ(p, di, dj)) {
                    const int i = a * a + di, j = b * b + dj;
                    float pr[TPV];
                    #pragma unroll
                    for (int v = 0; v < TPV; ++v)
                        pr[v] = xs[v * 9 + i] * ys[v * 9 + j];
                    #pragma unroll
                    for (int dk = 0; dk < 2 * c + 1; ++dk) {
                        const float kv = cg::KT.v[i][j][c * c + dk];
                        if (kv != 0.0f) {
                            #pragma unroll
                            for (int v = 0; v < TPV; ++v)
                                pv[dk][v] += kv * pr[v];
                        }
                    }
                }
            }
        }
        #pragma unroll
        for (int dk = 0; dk < 2 * c + 1; ++dk) {
            if (cg::rowNZp(p, dk)) {
                #pragma unroll
                for (int v = 0; v < TPV; ++v)
                    acc[v * 9 + c * c + dk] += w[p] * pv[dk][v];
            }
        }
    }

    // ---- direct strided float4 stores ----
    f4* og = reinterpret_cast<f4*>(out) + set * 9;
    #pragma unroll
    for (int q = 0; q < 9; ++q)
        og[q] = *reinterpret_cast<const f4*>(&acc[q * 4]);
}

// ===========================================================================

extern "C" void kernel_launch(void* const* d_in, const int* in_sizes, int n_in,
                              void* d_out, int out_size, void* d_ws, size_t ws_size,
                              hipStream_t stream) {
    const float* x   = (const float*)d_in[0];
    const float* y   = (const float*)d_in[1];
    const float* tpw = (const float*)d_in[2];
    const float* Wfx = (const float*)d_in[3];
    const float* bfx = (const float*)d_in[4];
    const float* Wfy = (const float*)d_in[5];
    const float* bfy = (const float*)d_in[6];
    float* out = (float*)d_out;

    long n_items = (long)out_size / 9;              // 16,777,216
    long n_sets = n_items / TPV;                    // 4,194,304
    long grid = n_sets / BLK;                       // 16,384 (exact)

    hipLaunchKernelGGL(tp_main_kernel, dim3((unsigned)grid), dim3(BLK), 0, stream,
                       x, y, out, tpw, Wfx, bfx, Wfy, bfy);
}